// Round 5
// baseline (39.213 us; speedup 1.0000x reference)
//
#include <hip/hip_runtime.h>
#include <math.h>

#define N 1536
#define NB 128   // buckets per channel

// ---------------- K1: node encoder + message projection ----------------
// 256 blocks x 512 threads; 6 rows/block (waves 0..5), float4 weight staging.
__global__ __launch_bounds__(512) void enc_kernel(
    const float* __restrict__ x, const float* __restrict__ W1, const float* __restrict__ b1,
    const float* __restrict__ W2, const float* __restrict__ b2,
    const float* __restrict__ Wm,
    float* __restrict__ h, float* __restrict__ p)
{
    __shared__ float sW2[64 * 64];
    __shared__ float sWm[64 * 64];
    __shared__ float buf1[6][64];
    __shared__ float buf2[6][64];
    int t = threadIdx.x;
    int w = t >> 6, c = t & 63;
    int i0 = blockIdx.x * 6;

    {
        const float4* W2v = (const float4*)W2;
        const float4* Wmv = (const float4*)Wm;
        float4* s2 = (float4*)sW2;
        float4* sm = (float4*)sWm;
        #pragma unroll
        for (int i = t; i < 1024; i += 512) { s2[i] = W2v[i]; sm[i] = Wmv[i]; }
    }

    if (w < 6) {
        int row = i0 + w;
        float4 xv = ((const float4*)x)[row];
        float h1 = xv.x * W1[0 * 64 + c] + xv.y * W1[1 * 64 + c]
                 + xv.z * W1[2 * 64 + c] + xv.w * W1[3 * 64 + c] + b1[c];
        buf1[w][c] = fmaxf(0.f, h1);
    }
    __syncthreads();

    if (w < 6) {
        int row = i0 + w;
        float h2 = b2[c];
        #pragma unroll
        for (int k = 0; k < 64; ++k) h2 = fmaf(buf1[w][k], sW2[k * 64 + c], h2);
        h2 = fmaxf(0.f, h2);
        h[row * 64 + c] = h2;
        buf2[w][c] = h2;

        float pv = 0.f;
        #pragma unroll
        for (int k = 0; k < 64; ++k) pv = fmaf(buf2[w][k], sWm[k * 64 + c], pv);
        p[row * 64 + c] = pv;
    }
}

// ---------------- K2: per-channel bucketization of p ----------------
// 64 blocks (one per channel) x 256 threads. Builds, per channel c:
//   bucketed[c*N + pos]       : p values grouped by bucket
//   bstart[c*(NB+1) + b]      : bucket start offsets (exclusive prefix)
//   SAe[c*(NB+1) + b]         : sum of values in buckets >= b   (SAe[NB]=0)
//   CAe[c*(NB+1) + b]         : count of values in buckets >= b (as float)
//   chanMin[c], chanScale[c]
__global__ __launch_bounds__(256) void bucket_kernel(
    const float* __restrict__ p,
    float* __restrict__ bucketed, int* __restrict__ bstart,
    float* __restrict__ SAe, float* __restrict__ CAe,
    float* __restrict__ chanMin, float* __restrict__ chanScale)
{
    int c = blockIdx.x;
    int t = threadIdx.x;
    __shared__ int   cnt[NB];
    __shared__ float bsum[NB];
    __shared__ int   boff[NB];
    __shared__ float redmin[4], redmax[4];

    float vloc[6];
    float mn = 1e30f, mx = -1e30f;
    #pragma unroll
    for (int u = 0; u < 6; ++u) {
        float v = p[(t + u * 256) * 64 + c];
        vloc[u] = v;
        mn = fminf(mn, v); mx = fmaxf(mx, v);
    }
    #pragma unroll
    for (int off = 32; off > 0; off >>= 1) {
        mn = fminf(mn, __shfl_down(mn, off));
        mx = fmaxf(mx, __shfl_down(mx, off));
    }
    int wid = t >> 6, lane = t & 63;
    if (lane == 0) { redmin[wid] = mn; redmax[wid] = mx; }
    if (t < NB) { cnt[t] = 0; bsum[t] = 0.f; }
    __syncthreads();

    mn = fminf(fminf(redmin[0], redmin[1]), fminf(redmin[2], redmin[3]));
    mx = fmaxf(fmaxf(redmax[0], redmax[1]), fmaxf(redmax[2], redmax[3]));
    float range = mx - mn;
    float scale = (float)NB / (range + range * 1e-6f + 1e-30f);

    int bl[6];
    #pragma unroll
    for (int u = 0; u < 6; ++u) {
        int b = (int)((vloc[u] - mn) * scale);
        b = b < 0 ? 0 : (b > NB - 1 ? NB - 1 : b);
        bl[u] = b;
        atomicAdd(&cnt[b], 1);
        atomicAdd(&bsum[b], vloc[u]);
    }
    __syncthreads();

    if (t < NB) {
        float s = 0.f, cc = 0.f;
        for (int b2 = t + 1; b2 < NB; ++b2) { s += bsum[b2]; cc += (float)cnt[b2]; }
        SAe[c * (NB + 1) + t + 1] = s;
        CAe[c * (NB + 1) + t + 1] = cc;
        if (t == 0) {
            SAe[c * (NB + 1)] = s + bsum[0];
            CAe[c * (NB + 1)] = cc + (float)cnt[0];
            chanMin[c] = mn;
            chanScale[c] = scale;
        }
        int pf = 0;
        for (int b2 = 0; b2 < t; ++b2) pf += cnt[b2];
        boff[t] = pf;
        bstart[c * (NB + 1) + t] = pf;
        if (t == NB - 1) bstart[c * (NB + 1) + NB] = N;
    }
    __syncthreads();

    #pragma unroll
    for (int u = 0; u < 6; ++u) {
        int pos = atomicAdd(&boff[bl[u]], 1);
        bucketed[c * N + pos] = vloc[u];
    }
}

// ---------------- K3: rank-query message pass + update MLP + heads ----------------
#define RI 6
__global__ __launch_bounds__(1024) void msg_upd_kernel(
    const float* __restrict__ p, const float* __restrict__ bm,
    const float* __restrict__ h,
    const float* __restrict__ bucketed, const int* __restrict__ bstart,
    const float* __restrict__ SAe, const float* __restrict__ CAe,
    const float* __restrict__ chanMin, const float* __restrict__ chanScale,
    const float* __restrict__ Wu1, const float* __restrict__ bu1,
    const float* __restrict__ Wu2, const float* __restrict__ bu2,
    const float* __restrict__ Wmean, const float* __restrict__ bmean,
    const float* __restrict__ Wv, const float* __restrict__ bv,
    const float* __restrict__ log_std,
    float* __restrict__ out)
{
    __shared__ float hu[RI][128];        // [h, msgs], reused for final u
    __shared__ float u1s[RI][128];
    __shared__ float part[8][RI][128];

    int t = threadIdx.x;
    int g = t >> 6, c = t & 63;
    int i0 = blockIdx.x * RI;

    // ---- phase A: rank query per (row, channel) ----
    if (t < RI * 64) {
        int r = t >> 6;
        float q = p[(i0 + r) * 64 + c] - bm[c];
        float mnv = chanMin[c], sc = chanScale[c];
        int bq = (int)floorf((q - mnv) * sc);
        float S, C;
        if (bq >= NB) { S = 0.f; C = 0.f; }
        else if (bq < 0) {
            S = SAe[c * (NB + 1)]; C = CAe[c * (NB + 1)];
        } else {
            S = SAe[c * (NB + 1) + bq + 1];
            C = CAe[c * (NB + 1) + bq + 1];
            int s0 = bstart[c * (NB + 1) + bq];
            int s1 = bstart[c * (NB + 1) + bq + 1];
            for (int idx = s0; idx < s1; ++idx) {
                float e = bucketed[c * N + idx];
                if (e > q) { S += e; C += 1.f; }
            }
        }
        hu[r][64 + c] = (S - C * q) * (1.0f / N);
    }
    // stage h rows into hu[:, 0:64] with spare threads
    if (t >= 512 && t < 512 + RI * 64) {
        int tt = t - 512;
        hu[tt >> 6][tt & 63] = h[(i0 + (tt >> 6)) * 64 + (tt & 63)];
    }
    __syncthreads();

    // ---- phase B: update MLP, k split across 8 groups of 16 ----
    int ch = t & 127, kh = t >> 7;
    {
        float u1[RI];
        #pragma unroll
        for (int r = 0; r < RI; ++r) u1[r] = 0.f;
        #pragma unroll
        for (int k = kh * 16; k < kh * 16 + 16; ++k) {
            float w = Wu1[k * 128 + ch];
            #pragma unroll
            for (int r = 0; r < RI; ++r) u1[r] = fmaf(hu[r][k], w, u1[r]);
        }
        #pragma unroll
        for (int r = 0; r < RI; ++r) part[kh][r][ch] = u1[r];
    }
    __syncthreads();
    if (t < RI * 128) {
        int r = t >> 7, cc = t & 127;
        float v = bu1[cc];
        #pragma unroll
        for (int kk = 0; kk < 8; ++kk) v += part[kk][r][cc];
        u1s[r][cc] = fmaxf(0.f, v);
    }
    __syncthreads();
    {
        float u2[RI];
        #pragma unroll
        for (int r = 0; r < RI; ++r) u2[r] = 0.f;
        #pragma unroll
        for (int k = kh * 16; k < kh * 16 + 16; ++k) {
            float w = Wu2[k * 128 + ch];
            #pragma unroll
            for (int r = 0; r < RI; ++r) u2[r] = fmaf(u1s[r][k], w, u2[r]);
        }
        #pragma unroll
        for (int r = 0; r < RI; ++r) part[kh][r][ch] = u2[r];
    }
    __syncthreads();
    if (t < RI * 128) {
        int r = t >> 7, cc = t & 127;
        float v = bu2[cc];
        #pragma unroll
        for (int kk = 0; kk < 8; ++kk) v += part[kk][r][cc];
        hu[r][cc] = fmaxf(0.f, v);
    }
    __syncthreads();

    // ---- heads ----
    if (g < RI) {
        int r = g, lane = c;
        float a  = hu[r][lane];
        float b2 = hu[r][lane + 64];
        float m0 = a * Wmean[lane * 2 + 0] + b2 * Wmean[(lane + 64) * 2 + 0];
        float m1 = a * Wmean[lane * 2 + 1] + b2 * Wmean[(lane + 64) * 2 + 1];
        float vv = a * Wv[lane]            + b2 * Wv[lane + 64];
        #pragma unroll
        for (int off = 32; off > 0; off >>= 1) {
            m0 += __shfl_down(m0, off);
            m1 += __shfl_down(m1, off);
            vv += __shfl_down(vv, off);
        }
        if (lane == 0) {
            int row = i0 + r;
            out[row * 2 + 0] = m0 + bmean[0];
            out[row * 2 + 1] = m1 + bmean[1];
            out[3074 + row]  = vv + bv[0];
        }
    }
    if (blockIdx.x == 0 && t < 2) {
        out[3072 + t] = expf(log_std[t]);
    }
}

extern "C" void kernel_launch(void* const* d_in, const int* in_sizes, int n_in,
                              void* d_out, int out_size, void* d_ws, size_t ws_size,
                              hipStream_t stream) {
    const float* x      = (const float*)d_in[0];
    const float* W1     = (const float*)d_in[1];
    const float* b1     = (const float*)d_in[2];
    const float* W2     = (const float*)d_in[3];
    const float* b2     = (const float*)d_in[4];
    const float* Wm     = (const float*)d_in[5];
    const float* bm     = (const float*)d_in[6];
    const float* Wu1    = (const float*)d_in[7];
    const float* bu1    = (const float*)d_in[8];
    const float* Wu2    = (const float*)d_in[9];
    const float* bu2    = (const float*)d_in[10];
    const float* Wmean  = (const float*)d_in[11];
    const float* bmean  = (const float*)d_in[12];
    const float* Wv     = (const float*)d_in[13];
    const float* bv     = (const float*)d_in[14];
    const float* log_std= (const float*)d_in[15];
    float* out = (float*)d_out;

    float* ws = (float*)d_ws;
    float* h        = ws;                      // N*64
    float* p        = ws + N * 64;             // N*64
    float* bucketed = ws + 2 * N * 64;         // 64*N
    int*   bstart   = (int*)(ws + 3 * N * 64); // 64*(NB+1)
    float* SAe      = ws + 3 * N * 64 + 64 * (NB + 1);
    float* CAe      = SAe + 64 * (NB + 1);
    float* chanMin  = CAe + 64 * (NB + 1);
    float* chanScale= chanMin + 64;

    enc_kernel<<<N / 6, 512, 0, stream>>>(x, W1, b1, W2, b2, Wm, h, p);
    bucket_kernel<<<64, 256, 0, stream>>>(p, bucketed, bstart, SAe, CAe,
                                          chanMin, chanScale);
    msg_upd_kernel<<<N / RI, 1024, 0, stream>>>(p, bm, h,
                                                bucketed, bstart, SAe, CAe, chanMin, chanScale,
                                                Wu1, bu1, Wu2, bu2,
                                                Wmean, bmean, Wv, bv, log_std, out);
}

// Round 6
// 22.651 us; speedup vs baseline: 1.7312x; 1.7312x over previous
//
#include <hip/hip_runtime.h>

#define N 1536

// ---------------- K1: node encoder + message projection ----------------
// 256 blocks x 512 threads; 6 rows/block (waves 0..5), float4 weight staging.
__global__ __launch_bounds__(512) void enc_kernel(
    const float* __restrict__ x, const float* __restrict__ W1, const float* __restrict__ b1,
    const float* __restrict__ W2, const float* __restrict__ b2,
    const float* __restrict__ Wm,
    float* __restrict__ h, float* __restrict__ p)
{
    __shared__ float sW2[64 * 64];
    __shared__ float sWm[64 * 64];
    __shared__ float buf1[6][64];
    __shared__ float buf2[6][64];
    int t = threadIdx.x;
    int w = t >> 6, c = t & 63;
    int i0 = blockIdx.x * 6;

    {
        const float4* W2v = (const float4*)W2;
        const float4* Wmv = (const float4*)Wm;
        float4* s2 = (float4*)sW2;
        float4* sm = (float4*)sWm;
        #pragma unroll
        for (int i = t; i < 1024; i += 512) { s2[i] = W2v[i]; sm[i] = Wmv[i]; }
    }

    if (w < 6) {
        int row = i0 + w;
        float4 xv = ((const float4*)x)[row];
        float h1 = xv.x * W1[0 * 64 + c] + xv.y * W1[1 * 64 + c]
                 + xv.z * W1[2 * 64 + c] + xv.w * W1[3 * 64 + c] + b1[c];
        buf1[w][c] = fmaxf(0.f, h1);
    }
    __syncthreads();

    if (w < 6) {
        int row = i0 + w;
        float h2 = b2[c];
        #pragma unroll
        for (int k = 0; k < 64; ++k) h2 = fmaf(buf1[w][k], sW2[k * 64 + c], h2);
        h2 = fmaxf(0.f, h2);
        h[row * 64 + c] = h2;
        buf2[w][c] = h2;

        float pv = 0.f;
        #pragma unroll
        for (int k = 0; k < 64; ++k) pv = fmaf(buf2[w][k], sWm[k * 64 + c], pv);
        p[row * 64 + c] = pv;
    }
}

// ---------------- K2: fused message pass + update MLP + heads ----------------
// 256 blocks x 1024 threads (16 waves). RI=6 rows per block.
// msgs[i,c] = (1/N)*(sum_j max(p[j,c], q) - N*q), q = p[i,c]-bm[c]
#define RI 6     // rows per block  (256 * 6 = 1536)
#define G  16    // j-groups (one per wave)
#define JPG (N / G)   // 96 j's per group, contiguous chunk
#define JB 16    // load batch depth (16 loads in flight per wave)
__global__ __launch_bounds__(1024) void msg_upd_kernel(
    const float* __restrict__ p, const float* __restrict__ bm,
    const float* __restrict__ h,
    const float* __restrict__ Wu1, const float* __restrict__ bu1,
    const float* __restrict__ Wu2, const float* __restrict__ bu2,
    const float* __restrict__ Wmean, const float* __restrict__ bmean,
    const float* __restrict__ Wv, const float* __restrict__ bv,
    const float* __restrict__ log_std,
    float* __restrict__ out)
{
    __shared__ float red[G][RI][64];     // 24 KB  (j-group partials)
    __shared__ float qs[RI][64];         // 1.5 KB (q values for finalize)
    __shared__ float hu[RI][128];        // 3 KB   ([h, msgs], reused for final u)
    __shared__ float u1s[RI][128];       // 3 KB
    __shared__ float part[8][RI][128];   // 24 KB  (k-split partials)

    int t = threadIdx.x;
    int c = t & 63, g = t >> 6;          // g in 0..15 (wave id)
    int i0 = blockIdx.x * RI;

    // ---- phase A ----
    float bmc = bm[c];
    float q[RI];
    #pragma unroll
    for (int r = 0; r < RI; ++r) q[r] = p[(i0 + r) * 64 + c] - bmc;
    if (g == 0) {
        #pragma unroll
        for (int r = 0; r < RI; ++r) qs[r][c] = q[r];
    }

    const float* pw = p + g * JPG * 64 + c;   // wave-contiguous j chunk
    float acc[RI];
    #pragma unroll
    for (int r = 0; r < RI; ++r) acc[r] = 0.f;

    float pj0[JB], pj1[JB];
    #pragma unroll
    for (int u = 0; u < JB; ++u) pj0[u] = pw[u * 64];

    #pragma unroll
    for (int jj = 0; jj < JPG / JB; ++jj) {   // 6 batches of 16
        if (jj + 1 < JPG / JB) {
            if ((jj & 1) == 0) {
                #pragma unroll
                for (int u = 0; u < JB; ++u) pj1[u] = pw[((jj + 1) * JB + u) * 64];
            } else {
                #pragma unroll
                for (int u = 0; u < JB; ++u) pj0[u] = pw[((jj + 1) * JB + u) * 64];
            }
        }
        if ((jj & 1) == 0) {
            #pragma unroll
            for (int u = 0; u < JB; ++u) {
                #pragma unroll
                for (int r = 0; r < RI; ++r) acc[r] += fmaxf(pj0[u], q[r]);
            }
        } else {
            #pragma unroll
            for (int u = 0; u < JB; ++u) {
                #pragma unroll
                for (int r = 0; r < RI; ++r) acc[r] += fmaxf(pj1[u], q[r]);
            }
        }
    }
    #pragma unroll
    for (int r = 0; r < RI; ++r) red[g][r][c] = acc[r];

    // stage h rows into hu[:, 0:64] (384 entries) with spare waves
    if (t >= 512 && t < 512 + RI * 64) {
        int tt = t - 512;
        hu[tt >> 6][tt & 63] = h[(i0 + (tt >> 6)) * 64 + (tt & 63)];
    }
    __syncthreads();

    // reduce 16 j-group partials, finalize with max-trick correction
    if (t < RI * 64) {
        int r = t >> 6, cc = t & 63;
        float s = 0.f;
        #pragma unroll
        for (int gg = 0; gg < G; ++gg) s += red[gg][r][cc];
        hu[r][64 + cc] = (s - (float)N * qs[r][cc]) * (1.0f / N);
    }
    __syncthreads();

    // ---- phase B: update MLP, k split across 8 groups of 16 ----
    int ch = t & 127, kh = t >> 7;
    {
        float u1[RI];
        #pragma unroll
        for (int r = 0; r < RI; ++r) u1[r] = 0.f;
        #pragma unroll
        for (int k = kh * 16; k < kh * 16 + 16; ++k) {
            float w = Wu1[k * 128 + ch];
            #pragma unroll
            for (int r = 0; r < RI; ++r) u1[r] = fmaf(hu[r][k], w, u1[r]);
        }
        #pragma unroll
        for (int r = 0; r < RI; ++r) part[kh][r][ch] = u1[r];
    }
    __syncthreads();
    if (t < RI * 128) {
        int r = t >> 7, cc = t & 127;
        float v = bu1[cc];
        #pragma unroll
        for (int kk = 0; kk < 8; ++kk) v += part[kk][r][cc];
        u1s[r][cc] = fmaxf(0.f, v);
    }
    __syncthreads();
    {
        float u2[RI];
        #pragma unroll
        for (int r = 0; r < RI; ++r) u2[r] = 0.f;
        #pragma unroll
        for (int k = kh * 16; k < kh * 16 + 16; ++k) {
            float w = Wu2[k * 128 + ch];
            #pragma unroll
            for (int r = 0; r < RI; ++r) u2[r] = fmaf(u1s[r][k], w, u2[r]);
        }
        #pragma unroll
        for (int r = 0; r < RI; ++r) part[kh][r][ch] = u2[r];
    }
    __syncthreads();
    if (t < RI * 128) {
        int r = t >> 7, cc = t & 127;
        float v = bu2[cc];
        #pragma unroll
        for (int kk = 0; kk < 8; ++kk) v += part[kk][r][cc];
        hu[r][cc] = fmaxf(0.f, v);
    }
    __syncthreads();

    // ---- heads: wave g < RI handles row g, 64-lane shuffle reduction ----
    if (g < RI) {
        int r = g, lane = c;
        float a  = hu[r][lane];
        float b2 = hu[r][lane + 64];
        float m0 = a * Wmean[lane * 2 + 0] + b2 * Wmean[(lane + 64) * 2 + 0];
        float m1 = a * Wmean[lane * 2 + 1] + b2 * Wmean[(lane + 64) * 2 + 1];
        float vv = a * Wv[lane]            + b2 * Wv[lane + 64];
        #pragma unroll
        for (int off = 32; off > 0; off >>= 1) {
            m0 += __shfl_down(m0, off);
            m1 += __shfl_down(m1, off);
            vv += __shfl_down(vv, off);
        }
        if (lane == 0) {
            int row = i0 + r;
            out[row * 2 + 0] = m0 + bmean[0];
            out[row * 2 + 1] = m1 + bmean[1];
            out[3074 + row]  = vv + bv[0];
        }
    }
    if (blockIdx.x == 0 && t < 2) {
        out[3072 + t] = expf(log_std[t]);
    }
}

extern "C" void kernel_launch(void* const* d_in, const int* in_sizes, int n_in,
                              void* d_out, int out_size, void* d_ws, size_t ws_size,
                              hipStream_t stream) {
    const float* x      = (const float*)d_in[0];
    const float* W1     = (const float*)d_in[1];
    const float* b1     = (const float*)d_in[2];
    const float* W2     = (const float*)d_in[3];
    const float* b2     = (const float*)d_in[4];
    const float* Wm     = (const float*)d_in[5];
    const float* bm     = (const float*)d_in[6];
    const float* Wu1    = (const float*)d_in[7];
    const float* bu1    = (const float*)d_in[8];
    const float* Wu2    = (const float*)d_in[9];
    const float* bu2    = (const float*)d_in[10];
    const float* Wmean  = (const float*)d_in[11];
    const float* bmean  = (const float*)d_in[12];
    const float* Wv     = (const float*)d_in[13];
    const float* bv     = (const float*)d_in[14];
    const float* log_std= (const float*)d_in[15];
    float* out = (float*)d_out;

    float* ws = (float*)d_ws;
    float* h  = ws;              // N*64
    float* p  = ws + N * 64;     // N*64

    enc_kernel<<<N / 6, 512, 0, stream>>>(x, W1, b1, W2, b2, Wm, h, p);
    msg_upd_kernel<<<N / RI, 1024, 0, stream>>>(p, bm, h, Wu1, bu1, Wu2, bu2,
                                                Wmean, bmean, Wv, bv, log_std, out);
}